// Round 10
// baseline (175.035 us; speedup 1.0000x reference)
//
#include <hip/hip_runtime.h>

#define NN 10000     // nodes
#define HF 128       // hidden feats
#define INF_ 256     // in feats
#define CLS 64       // classes
#define NR 8         // bucket segments (one per XCD)
#define SEG 32       // slots per segment (64B line); per-seg deg ~Poisson(8), P(>32)~1e-13
#define CAPT (NR * SEG)   // 256 slots/node
#define NP 10240     // cnt8 per-replica stride (ints)
#define RT  (NN / 16)  // 625 row tiles
#define LDP (HF + 8)   // padded LDS row stride (shorts): 272B -> 2-way conflicts only

typedef __attribute__((ext_vector_type(8))) short short8;   // 8 bf16 (4 VGPRs)
typedef __attribute__((ext_vector_type(4))) float f32x4;

__device__ __forceinline__ unsigned short f2bf(float f) {
    unsigned u = __builtin_bit_cast(unsigned, f);
    u = (u + 0x7fffu + ((u >> 16) & 1u)) >> 16;   // RNE
    return (unsigned short)u;
}
__device__ __forceinline__ float bfbits2f(unsigned u) {  // u = bf16 in low 16
    u <<= 16;
    return __builtin_bit_cast(float, u);
}

// ---------------- MFMA helpers ----------------
// Verified gfx950 fragment layouts (learn_hip m89/m120):
//   A frag: lane holds A[m=lane&15][k=(lane>>4)*8 + 0..7]  (16B contiguous)
//   B frag: lane holds W[n=lane&15][k=(lane>>4)*8 + 0..7]  (W row-major [N][K] = B^T)
//   C/D:    col=lane&15, row=(lane>>4)*4 + reg
// lda = row stride of A in elements (HF for global, LDP for padded LDS).

template <int K, int NC>
__device__ __forceinline__
void mfma_cols(int row_tile, int col0,
               const unsigned short* __restrict__ A, int lda,
               const unsigned short* __restrict__ W, f32x4* acc) {
    int lane = threadIdx.x & 63;
    int m = lane & 15, quad = lane >> 4;
    const unsigned short* arow = A + (size_t)(row_tile * 16 + m) * lda + quad * 8;
    const short8* bp[NC];
#pragma unroll
    for (int c = 0; c < NC; ++c)
        bp[c] = (const short8*)(W + (size_t)(col0 + c * 16 + m) * K + quad * 8);
#pragma unroll
    for (int k0 = 0; k0 < K; k0 += 32) {
        short8 a = *(const short8*)(arow + k0);
#pragma unroll
        for (int c = 0; c < NC; ++c)
            acc[c] = __builtin_amdgcn_mfma_f32_16x16x32_bf16(a, bp[c][k0 >> 3], acc[c], 0, 0, 0);
    }
}

template <int NC, bool OUT_BF16, bool RELU_OUT, bool HAS_BIAS>
__device__ __forceinline__
void epilogue_n(int row_tile, int col0, int N, const float* __restrict__ bias,
                f32x4* acc, void* __restrict__ out) {
    int lane = threadIdx.x & 63;
    int m = lane & 15, quad = lane >> 4;
#pragma unroll
    for (int c = 0; c < NC; ++c) {
        int colg = col0 + c * 16 + m;
        float bv = HAS_BIAS ? bias[colg] : 0.f;
#pragma unroll
        for (int r = 0; r < 4; ++r) {
            int rowg = row_tile * 16 + quad * 4 + r;
            float v = acc[c][r] + bv;
            if (RELU_OUT) v = fmaxf(v, 0.f);
            if (OUT_BF16) ((unsigned short*)out)[(size_t)rowg * N + colg] = f2bf(v);
            else          ((float*)out)[(size_t)rowg * N + colg] = v;
        }
    }
}

__device__ __forceinline__ short8 pack8(float4 a, float4 b) {
    short8 r;
    r[0] = (short)f2bf(a.x); r[1] = (short)f2bf(a.y);
    r[2] = (short)f2bf(a.z); r[3] = (short)f2bf(a.w);
    r[4] = (short)f2bf(b.x); r[5] = (short)f2bf(b.y);
    r[6] = (short)f2bf(b.z); r[7] = (short)f2bf(b.w);
    return r;
}

// input projection: h0 = relu(x @ W_lin.T + b_lin); x, W_lin f32 (cvt in-loop —
// hides under the latency-bound fill anyway)
__device__ __forceinline__
void gemm1_wave(int row_tile, int col0, const float* __restrict__ x,
                const float* __restrict__ Wlin, const float* __restrict__ blin,
                unsigned short* __restrict__ h0) {
    int lane = threadIdx.x & 63;
    int m = lane & 15, quad = lane >> 4;
    const float* ar = x    + (size_t)(row_tile * 16 + m) * INF_ + quad * 8;
    const float* w0 = Wlin + (size_t)(col0 +  0 + m) * INF_ + quad * 8;
    const float* w1 = Wlin + (size_t)(col0 + 16 + m) * INF_ + quad * 8;
    const float* w2 = Wlin + (size_t)(col0 + 32 + m) * INF_ + quad * 8;
    const float* w3 = Wlin + (size_t)(col0 + 48 + m) * INF_ + quad * 8;
    f32x4 acc[4] = {};
#pragma unroll
    for (int k0 = 0; k0 < INF_; k0 += 32) {
        short8 a  = pack8(*(const float4*)(ar + k0), *(const float4*)(ar + k0 + 4));
        short8 b0 = pack8(*(const float4*)(w0 + k0), *(const float4*)(w0 + k0 + 4));
        short8 b1 = pack8(*(const float4*)(w1 + k0), *(const float4*)(w1 + k0 + 4));
        short8 b2 = pack8(*(const float4*)(w2 + k0), *(const float4*)(w2 + k0 + 4));
        short8 b3 = pack8(*(const float4*)(w3 + k0), *(const float4*)(w3 + k0 + 4));
        acc[0] = __builtin_amdgcn_mfma_f32_16x16x32_bf16(a, b0, acc[0], 0, 0, 0);
        acc[1] = __builtin_amdgcn_mfma_f32_16x16x32_bf16(a, b1, acc[1], 0, 0, 0);
        acc[2] = __builtin_amdgcn_mfma_f32_16x16x32_bf16(a, b2, acc[2], 0, 0, 0);
        acc[3] = __builtin_amdgcn_mfma_f32_16x16x32_bf16(a, b3, acc[3], 0, 0, 0);
    }
    epilogue_n<4, true, true, true>(row_tile, col0, HF, blin, acc, h0);
}

// ---------------- fused: gemm1 || segmented bucket fill || weight cvt ----------------
#define GB 313    // gemm1 blocks (2 row-tiles each, covers 625)
#define FB 2500   // fill blocks: 1 edge/thread (R6 lesson: waves > per-thread ILP)
#define CB 288    // weight-convert blocks (73728/256)

__global__ __launch_bounds__(256)
void fused_k(const float* __restrict__ x, const float* __restrict__ Wlin,
             const float* __restrict__ blin, unsigned short* __restrict__ h0,
             const int* __restrict__ src, const int* __restrict__ dst,
             int* __restrict__ cnt8, unsigned short* __restrict__ colb, int E,
             const float* __restrict__ Wl1, const float* __restrict__ Wr1,
             const float* __restrict__ Wl2, const float* __restrict__ Wr2,
             const float* __restrict__ Wcls, unsigned short* __restrict__ wb) {
    int b = blockIdx.x;
    if (b < GB) {
        int wave = threadIdx.x >> 6;
        int row_tile = b * 2 + (wave >> 1);
        if (row_tile >= RT) return;
        gemm1_wave(row_tile, (wave & 1) * 64, x, Wlin, blin, h0);
    } else if (b < GB + FB) {
        // XCD-segmented scatter: replica r = blockIdx%8 tracks the round-robin
        // block->XCD dispatch, so each 64B colb segment line is written by ONE
        // XCD only -> no cross-XCD line bouncing (R9: 32.8MB WRITE_SIZE for a
        // 2.5MB array).
        int r = b & 7;
        int i = (b - GB) * 256 + threadIdx.x;
        if (i < E) {
            int d = dst[i];
            int pos = atomicAdd(&cnt8[r * NP + d], 1);
            if (pos < SEG) colb[(size_t)d * CAPT + r * SEG + pos] = (unsigned short)src[i];
        }
    } else {
        int i = (b - GB - FB) * 256 + threadIdx.x;
        const float* s; int off;
        if      (i < 16384) { s = Wl1;  off = 0; }
        else if (i < 32768) { s = Wr1;  off = 16384; }
        else if (i < 49152) { s = Wl2;  off = 32768; }
        else if (i < 65536) { s = Wr2;  off = 49152; }
        else if (i < 73728) { s = Wcls; off = 65536; }
        else return;
        wb[i] = f2bf(s[i - off]);
    }
}

// ---------------- per-wave mean gather (segmented) into an LDS row ----------------
// 8 independent segment chains (idx load -> shfl -> 4-quad row gather) give
// natural MLP. quad layout: 16 lanes x uint4 cover a 256B bf16 row; 4
// lane-groups process edges e%4==q. __shfl all-lanes-active (ds_bpermute
// respects EXEC, R2 bug); inner break is wave-uniform.
__device__ __forceinline__
void gather_mean(const unsigned short* __restrict__ h,
                 const int* __restrict__ cnt8, int node,
                 const unsigned short* __restrict__ seg,   // colb + node*CAPT
                 unsigned short* __restrict__ msrow) {
    int lane = threadIdx.x & 63;
    int q   = lane >> 4;
    int r16 = lane & 15;
    const uint4* __restrict__ hp = (const uint4*)h;   // bf16 row = 16 uint4

    float a0 = 0.f, a1 = 0.f, a2 = 0.f, a3 = 0.f;
    float a4 = 0.f, a5 = 0.f, a6 = 0.f, a7 = 0.f;
    int deg = 0;
#pragma unroll
    for (int r = 0; r < NR; ++r) {
        int craw = cnt8[r * NP + node];
        deg += craw;
        int c = craw > SEG ? SEG : craw;
        int colv = (int)seg[r * SEG + (lane & 31)];   // lanes 32-63 mirror 0-31
#pragma unroll
        for (int jj = 0; jj < SEG / 4; ++jj) {
            if (jj * 4 >= c) break;                   // wave-uniform break
            int e = jj * 4 + q;
            int s = __shfl(colv, e);                  // all lanes active; src<32
            if (e < c) {
                uint4 v = hp[(size_t)s * 16 + r16];
                a0 += bfbits2f(v.x & 0xffffu); a1 += bfbits2f(v.x >> 16);
                a2 += bfbits2f(v.y & 0xffffu); a3 += bfbits2f(v.y >> 16);
                a4 += bfbits2f(v.z & 0xffffu); a5 += bfbits2f(v.z >> 16);
                a6 += bfbits2f(v.w & 0xffffu); a7 += bfbits2f(v.w >> 16);
            }
        }
    }
    // reduce across the 4 lane-groups (bits 4,5) — all lanes active
    a0 += __shfl_xor(a0, 16); a0 += __shfl_xor(a0, 32);
    a1 += __shfl_xor(a1, 16); a1 += __shfl_xor(a1, 32);
    a2 += __shfl_xor(a2, 16); a2 += __shfl_xor(a2, 32);
    a3 += __shfl_xor(a3, 16); a3 += __shfl_xor(a3, 32);
    a4 += __shfl_xor(a4, 16); a4 += __shfl_xor(a4, 32);
    a5 += __shfl_xor(a5, 16); a5 += __shfl_xor(a5, 32);
    a6 += __shfl_xor(a6, 16); a6 += __shfl_xor(a6, 32);
    a7 += __shfl_xor(a7, 16); a7 += __shfl_xor(a7, 32);
    if (q == 0) {
        float inv = (deg > 0) ? 1.0f / (float)deg : 0.f;
        uint4 o;
        o.x = (unsigned)f2bf(a0 * inv) | ((unsigned)f2bf(a1 * inv) << 16);
        o.y = (unsigned)f2bf(a2 * inv) | ((unsigned)f2bf(a3 * inv) << 16);
        o.z = (unsigned)f2bf(a4 * inv) | ((unsigned)f2bf(a5 * inv) << 16);
        o.w = (unsigned)f2bf(a6 * inv) | ((unsigned)f2bf(a7 * inv) << 16);
        ((uint4*)msrow)[r16] = o;
    }
}

// ---------------- aggfin1: agg + full sage1 GEMM in one block ----------------
// 1024 threads = 16 waves = 16 nodes = one MFMA row-tile (block b <-> tile b).
// All waves gather their node's mean -> LDS. Waves 0-7 pre-compute h0@Wr1
// (global reads, overlaps straggler gathers), then after the barrier add
// means@Wl1 (LDS A-operand) + bias and write h1.
__global__ __launch_bounds__(1024)
void aggfin1_k(const unsigned short* __restrict__ h0, const int* __restrict__ cnt8,
               const unsigned short* __restrict__ colb,
               const unsigned short* __restrict__ Wr, const unsigned short* __restrict__ Wl,
               const float* __restrict__ bias, unsigned short* __restrict__ h1) {
    __shared__ __align__(16) unsigned short ms[16][LDP];
    int wave = threadIdx.x >> 6;
    int node = blockIdx.x * 16 + wave;        // NN = 625*16 exactly
    gather_mean(h0, cnt8, node, colb + (size_t)node * CAPT, &ms[wave][0]);

    f32x4 acc[1] = {};
    if (wave < 8)
        mfma_cols<HF, 1>(blockIdx.x, wave * 16, h0, HF, Wr, acc);  // h0 @ Wr1
    __syncthreads();
    if (wave < 8) {
        mfma_cols<HF, 1>(0, wave * 16, &ms[0][0], LDP, Wl, acc);   // + means @ Wl1
        epilogue_n<1, true, false, true>(blockIdx.x, wave * 16, HF, bias, acc, h1);
    }
}

// ---------------- aggfin2cls: agg + sage2 GEMM + relu + classifier ----------------
// Same structure; h2 row-tile lives only in LDS (padded), classifier runs from it.
__global__ __launch_bounds__(1024)
void aggfin2cls_k(const unsigned short* __restrict__ h1, const int* __restrict__ cnt8,
                  const unsigned short* __restrict__ colb,
                  const unsigned short* __restrict__ Wr, const unsigned short* __restrict__ Wl,
                  const float* __restrict__ bias, const unsigned short* __restrict__ Wc,
                  float* __restrict__ out) {
    __shared__ __align__(16) unsigned short ms[16][LDP];
    __shared__ __align__(16) unsigned short h2s[16][LDP];
    int wave = threadIdx.x >> 6;
    int lane = threadIdx.x & 63;
    int m = lane & 15, quad = lane >> 4;
    int node = blockIdx.x * 16 + wave;
    gather_mean(h1, cnt8, node, colb + (size_t)node * CAPT, &ms[wave][0]);

    f32x4 acc[1] = {};
    if (wave < 8)
        mfma_cols<HF, 1>(blockIdx.x, wave * 16, h1, HF, Wr, acc);  // h1 @ Wr2
    __syncthreads();
    if (wave < 8) {
        mfma_cols<HF, 1>(0, wave * 16, &ms[0][0], LDP, Wl, acc);   // + means @ Wl2
        int colg = wave * 16 + m;
        float bv = bias[colg];
#pragma unroll
        for (int r = 0; r < 4; ++r) {
            float v = acc[0][r] + bv;
            h2s[quad * 4 + r][colg] = f2bf(fmaxf(v, 0.f));         // relu -> LDS
        }
    }
    __syncthreads();
    if (wave < 4) {
        f32x4 cacc[1] = {};
        mfma_cols<HF, 1>(0, wave * 16, &h2s[0][0], LDP, Wc, cacc); // h2 @ W_cls
        epilogue_n<1, false, false, false>(blockIdx.x, wave * 16, CLS,
                                           nullptr, cacc, out);
    }
}

// ---------------- launch ----------------

extern "C" void kernel_launch(void* const* d_in, const int* in_sizes, int n_in,
                              void* d_out, int out_size, void* d_ws, size_t ws_size,
                              hipStream_t stream) {
    const float* x      = (const float*)d_in[0];
    const int*   ei     = (const int*)d_in[1];
    const float* W_lin  = (const float*)d_in[2];
    const float* b_lin  = (const float*)d_in[3];
    const float* Wl1    = (const float*)d_in[4];
    const float* bl1    = (const float*)d_in[5];
    const float* Wr1    = (const float*)d_in[6];
    const float* Wl2    = (const float*)d_in[7];
    const float* bl2    = (const float*)d_in[8];
    const float* Wr2    = (const float*)d_in[9];
    const float* W_cls  = (const float*)d_in[10];
    float* out = (float*)d_out;

    const int E = in_sizes[1] / 2;
    const int* src = ei;
    const int* dst = ei + E;

    // workspace layout (bf16 stored as ushort)
    unsigned short* wb  = (unsigned short*)d_ws;          // 73728 weights bf16
    unsigned short* wbl1 = wb;
    unsigned short* wbr1 = wb + 16384;
    unsigned short* wbl2 = wb + 32768;
    unsigned short* wbr2 = wb + 49152;
    unsigned short* wbc  = wb + 65536;
    unsigned short* h0  = wb + 73728;                     // NN*HF
    unsigned short* h1  = h0 + (size_t)NN * HF;           // NN*HF
    int* cnt8 = (int*)(h1 + (size_t)NN * HF);             // NR*NP
    unsigned short* colb = (unsigned short*)(cnt8 + NR * NP);  // NN*CAPT

    hipMemsetAsync(cnt8, 0, NR * NP * sizeof(int), stream);

    // ---- fused: input projection + relu || segmented fill || weight cvt ----
    fused_k<<<GB + FB + CB, 256, 0, stream>>>(
        x, W_lin, b_lin, h0, src, dst, cnt8, colb, E,
        Wl1, Wr1, Wl2, Wr2, W_cls, wb);

    // ---- sage1 (agg + GEMM fused) ----
    aggfin1_k<<<RT, 1024, 0, stream>>>(h0, cnt8, colb, wbr1, wbl1, bl1, h1);

    // ---- sage2 + relu + classifier (agg + GEMMs fused) ----
    aggfin2cls_k<<<RT, 1024, 0, stream>>>(h1, cnt8, colb, wbr2, wbl2, bl2, wbc, out);
}

// Round 11
// 160.760 us; speedup vs baseline: 1.0888x; 1.0888x over previous
//
#include <hip/hip_runtime.h>

#define NN 10000     // nodes
#define HF 128       // hidden feats
#define INF_ 256     // in feats
#define CLS 64       // classes
#define NR 8         // bucket segments (one per XCD)
#define SEG 32       // slots per segment (64B line); per-seg deg ~Poisson(8), P(>32)~1e-13
#define CAPT (NR * SEG)   // 256 slots/node
#define NP 10240     // cnt8 per-replica stride (ints)
#define RT  (NN / 16)  // 625 row tiles
#define LDP (HF + 8)   // padded LDS row stride (shorts): 272B -> 2-way conflicts only

typedef __attribute__((ext_vector_type(8))) short short8;   // 8 bf16 (4 VGPRs)
typedef __attribute__((ext_vector_type(4))) float f32x4;

__device__ __forceinline__ unsigned short f2bf(float f) {
    unsigned u = __builtin_bit_cast(unsigned, f);
    u = (u + 0x7fffu + ((u >> 16) & 1u)) >> 16;   // RNE
    return (unsigned short)u;
}
__device__ __forceinline__ float bfbits2f(unsigned u) {  // u = bf16 in low 16
    u <<= 16;
    return __builtin_bit_cast(float, u);
}

// ---------------- MFMA helpers ----------------
// Verified gfx950 fragment layouts (learn_hip m89/m120):
//   A frag: lane holds A[m=lane&15][k=(lane>>4)*8 + 0..7]  (16B contiguous)
//   B frag: lane holds W[n=lane&15][k=(lane>>4)*8 + 0..7]  (W row-major [N][K] = B^T)
//   C/D:    col=lane&15, row=(lane>>4)*4 + reg
// lda = row stride of A in elements (HF for global, LDP for padded LDS).

template <int K, int NC>
__device__ __forceinline__
void mfma_cols(int row_tile, int col0,
               const unsigned short* __restrict__ A, int lda,
               const unsigned short* __restrict__ W, f32x4* acc) {
    int lane = threadIdx.x & 63;
    int m = lane & 15, quad = lane >> 4;
    const unsigned short* arow = A + (size_t)(row_tile * 16 + m) * lda + quad * 8;
    const short8* bp[NC];
#pragma unroll
    for (int c = 0; c < NC; ++c)
        bp[c] = (const short8*)(W + (size_t)(col0 + c * 16 + m) * K + quad * 8);
#pragma unroll
    for (int k0 = 0; k0 < K; k0 += 32) {
        short8 a = *(const short8*)(arow + k0);
#pragma unroll
        for (int c = 0; c < NC; ++c)
            acc[c] = __builtin_amdgcn_mfma_f32_16x16x32_bf16(a, bp[c][k0 >> 3], acc[c], 0, 0, 0);
    }
}

template <int NC, bool OUT_BF16, bool RELU_OUT, bool HAS_BIAS>
__device__ __forceinline__
void epilogue_n(int row_tile, int col0, int N, const float* __restrict__ bias,
                f32x4* acc, void* __restrict__ out) {
    int lane = threadIdx.x & 63;
    int m = lane & 15, quad = lane >> 4;
#pragma unroll
    for (int c = 0; c < NC; ++c) {
        int colg = col0 + c * 16 + m;
        float bv = HAS_BIAS ? bias[colg] : 0.f;
#pragma unroll
        for (int r = 0; r < 4; ++r) {
            int rowg = row_tile * 16 + quad * 4 + r;
            float v = acc[c][r] + bv;
            if (RELU_OUT) v = fmaxf(v, 0.f);
            if (OUT_BF16) ((unsigned short*)out)[(size_t)rowg * N + colg] = f2bf(v);
            else          ((float*)out)[(size_t)rowg * N + colg] = v;
        }
    }
}

__device__ __forceinline__ short8 pack8(float4 a, float4 b) {
    short8 r;
    r[0] = (short)f2bf(a.x); r[1] = (short)f2bf(a.y);
    r[2] = (short)f2bf(a.z); r[3] = (short)f2bf(a.w);
    r[4] = (short)f2bf(b.x); r[5] = (short)f2bf(b.y);
    r[6] = (short)f2bf(b.z); r[7] = (short)f2bf(b.w);
    return r;
}

// input projection: h0 = relu(x @ W_lin.T + b_lin); x, W_lin f32 (cvt in-loop —
// hides under the latency-bound fill anyway)
__device__ __forceinline__
void gemm1_wave(int row_tile, int col0, const float* __restrict__ x,
                const float* __restrict__ Wlin, const float* __restrict__ blin,
                unsigned short* __restrict__ h0) {
    int lane = threadIdx.x & 63;
    int m = lane & 15, quad = lane >> 4;
    const float* ar = x    + (size_t)(row_tile * 16 + m) * INF_ + quad * 8;
    const float* w0 = Wlin + (size_t)(col0 +  0 + m) * INF_ + quad * 8;
    const float* w1 = Wlin + (size_t)(col0 + 16 + m) * INF_ + quad * 8;
    const float* w2 = Wlin + (size_t)(col0 + 32 + m) * INF_ + quad * 8;
    const float* w3 = Wlin + (size_t)(col0 + 48 + m) * INF_ + quad * 8;
    f32x4 acc[4] = {};
#pragma unroll
    for (int k0 = 0; k0 < INF_; k0 += 32) {
        short8 a  = pack8(*(const float4*)(ar + k0), *(const float4*)(ar + k0 + 4));
        short8 b0 = pack8(*(const float4*)(w0 + k0), *(const float4*)(w0 + k0 + 4));
        short8 b1 = pack8(*(const float4*)(w1 + k0), *(const float4*)(w1 + k0 + 4));
        short8 b2 = pack8(*(const float4*)(w2 + k0), *(const float4*)(w2 + k0 + 4));
        short8 b3 = pack8(*(const float4*)(w3 + k0), *(const float4*)(w3 + k0 + 4));
        acc[0] = __builtin_amdgcn_mfma_f32_16x16x32_bf16(a, b0, acc[0], 0, 0, 0);
        acc[1] = __builtin_amdgcn_mfma_f32_16x16x32_bf16(a, b1, acc[1], 0, 0, 0);
        acc[2] = __builtin_amdgcn_mfma_f32_16x16x32_bf16(a, b2, acc[2], 0, 0, 0);
        acc[3] = __builtin_amdgcn_mfma_f32_16x16x32_bf16(a, b3, acc[3], 0, 0, 0);
    }
    epilogue_n<4, true, true, true>(row_tile, col0, HF, blin, acc, h0);
}

// ---------------- fused: gemm1 || segmented bucket fill || weight cvt ----------------
#define GB 313    // gemm1 blocks (2 row-tiles each, covers 625)
#define FB 2500   // fill blocks: 1 edge/thread (R6 lesson: waves > per-thread ILP)
#define CB 288    // weight-convert blocks (73728/256)

__global__ __launch_bounds__(256)
void fused_k(const float* __restrict__ x, const float* __restrict__ Wlin,
             const float* __restrict__ blin, unsigned short* __restrict__ h0,
             const int* __restrict__ src, const int* __restrict__ dst,
             int* __restrict__ cnt8, unsigned short* __restrict__ colb, int E,
             const float* __restrict__ Wl1, const float* __restrict__ Wr1,
             const float* __restrict__ Wl2, const float* __restrict__ Wr2,
             const float* __restrict__ Wcls, unsigned short* __restrict__ wb) {
    int b = blockIdx.x;
    if (b < GB) {
        int wave = threadIdx.x >> 6;
        int row_tile = b * 2 + (wave >> 1);
        if (row_tile >= RT) return;
        gemm1_wave(row_tile, (wave & 1) * 64, x, Wlin, blin, h0);
    } else if (b < GB + FB) {
        // XCD-segmented scatter: replica r = blockIdx%8 tracks the round-robin
        // block->XCD dispatch, so each 64B colb segment line is written by ONE
        // XCD only -> no cross-XCD line bouncing (R9: 32.8MB WRITE_SIZE for a
        // 2.5MB array).
        int r = b & 7;
        int i = (b - GB) * 256 + threadIdx.x;
        if (i < E) {
            int d = dst[i];
            int pos = atomicAdd(&cnt8[r * NP + d], 1);
            if (pos < SEG) colb[(size_t)d * CAPT + r * SEG + pos] = (unsigned short)src[i];
        }
    } else {
        int i = (b - GB - FB) * 256 + threadIdx.x;
        const float* s; int off;
        if      (i < 16384) { s = Wl1;  off = 0; }
        else if (i < 32768) { s = Wr1;  off = 16384; }
        else if (i < 49152) { s = Wl2;  off = 32768; }
        else if (i < 65536) { s = Wr2;  off = 49152; }
        else if (i < 73728) { s = Wcls; off = 65536; }
        else return;
        wb[i] = f2bf(s[i - off]);
    }
}

// ---------------- per-wave mean gather: compact segments -> flat LDS list ----
// Phase A: compact the 8 segments into cols[0..cdeg) in LDS (4 passes of
//   64-lane coalesced 64B reads; offsets via all-lane shfls — R2 rule).
// Phase B: ONE flat gather loop, 4 quad-edges/step; edge index read straight
//   from LDS (16-lane broadcast ds_read_u16, no shfl in the hot loop so the
//   tail guard is safe); unroll 4 -> >=4 independent 256B row-gathers in
//   flight. (R10 lesson: 8 short per-segment loops killed pipelining.)
__device__ __forceinline__
void gather_mean(const unsigned short* __restrict__ h,
                 const int* __restrict__ cnt8, int node,
                 const unsigned short* __restrict__ seg,   // colb + node*CAPT
                 unsigned short* __restrict__ cols,        // per-wave LDS, CAPT slots
                 unsigned short* __restrict__ msrow) {
    int lane = threadIdx.x & 63;
    int q   = lane >> 4;
    int r16 = lane & 15;

    // segment counts -> lanes 0..7
    int craw0 = 0;
    if (lane < 8) craw0 = cnt8[lane * NP + node];
    int c0 = craw0 > SEG ? SEG : craw0;
    int off0 = 0, deg = 0, cdeg = 0;
#pragma unroll
    for (int i = 0; i < 8; ++i) {                 // all-lanes-active shfls
        int ci = __shfl(c0, i);
        int ri = __shfl(craw0, i);
        if (lane > i) off0 += ci;                 // exclusive prefix (lanes 0..7)
        cdeg += ci;
        deg  += ri;
    }
    // compact: pass p covers segments 2p (lanes 0-31) and 2p+1 (lanes 32-63)
#pragma unroll
    for (int p = 0; p < 4; ++p) {
        int r = 2 * p + (lane >> 5);
        int j = lane & 31;
        unsigned short v = seg[r * SEG + j];      // coalesced 64B per segment
        int cr  = __shfl(c0, r);                  // all-lanes-active
        int orr = __shfl(off0, r);
        if (j < cr) cols[orr + j] = v;
    }

    const uint4* __restrict__ hp = (const uint4*)h;   // bf16 row = 16 uint4
    float a0 = 0.f, a1 = 0.f, a2 = 0.f, a3 = 0.f;
    float a4 = 0.f, a5 = 0.f, a6 = 0.f, a7 = 0.f;
#pragma unroll 4
    for (int e0 = 0; e0 < cdeg; e0 += 4) {
        int e = e0 + q;
        if (e < cdeg) {                            // no shfl inside: safe guard
            int s = (int)cols[e];                  // LDS u16, 16-lane broadcast
            uint4 v = hp[(size_t)s * 16 + r16];
            a0 += bfbits2f(v.x & 0xffffu); a1 += bfbits2f(v.x >> 16);
            a2 += bfbits2f(v.y & 0xffffu); a3 += bfbits2f(v.y >> 16);
            a4 += bfbits2f(v.z & 0xffffu); a5 += bfbits2f(v.z >> 16);
            a6 += bfbits2f(v.w & 0xffffu); a7 += bfbits2f(v.w >> 16);
        }
    }
    // reduce across the 4 lane-groups (bits 4,5) — all lanes active
    a0 += __shfl_xor(a0, 16); a0 += __shfl_xor(a0, 32);
    a1 += __shfl_xor(a1, 16); a1 += __shfl_xor(a1, 32);
    a2 += __shfl_xor(a2, 16); a2 += __shfl_xor(a2, 32);
    a3 += __shfl_xor(a3, 16); a3 += __shfl_xor(a3, 32);
    a4 += __shfl_xor(a4, 16); a4 += __shfl_xor(a4, 32);
    a5 += __shfl_xor(a5, 16); a5 += __shfl_xor(a5, 32);
    a6 += __shfl_xor(a6, 16); a6 += __shfl_xor(a6, 32);
    a7 += __shfl_xor(a7, 16); a7 += __shfl_xor(a7, 32);
    if (q == 0) {
        float inv = (deg > 0) ? 1.0f / (float)deg : 0.f;
        uint4 o;
        o.x = (unsigned)f2bf(a0 * inv) | ((unsigned)f2bf(a1 * inv) << 16);
        o.y = (unsigned)f2bf(a2 * inv) | ((unsigned)f2bf(a3 * inv) << 16);
        o.z = (unsigned)f2bf(a4 * inv) | ((unsigned)f2bf(a5 * inv) << 16);
        o.w = (unsigned)f2bf(a6 * inv) | ((unsigned)f2bf(a7 * inv) << 16);
        ((uint4*)msrow)[r16] = o;
    }
}

// ---------------- aggfin1: agg + full sage1 GEMM in one block ----------------
// 1024 threads = 16 waves = 16 nodes = one MFMA row-tile (block b <-> tile b).
// All waves gather their node's mean -> LDS. Waves 0-7 pre-compute h0@Wr1
// (global reads, overlaps straggler gathers), then after the barrier add
// means@Wl1 (LDS A-operand) + bias and write h1.
__global__ __launch_bounds__(1024)
void aggfin1_k(const unsigned short* __restrict__ h0, const int* __restrict__ cnt8,
               const unsigned short* __restrict__ colb,
               const unsigned short* __restrict__ Wr, const unsigned short* __restrict__ Wl,
               const float* __restrict__ bias, unsigned short* __restrict__ h1) {
    __shared__ __align__(16) unsigned short ms[16][LDP];
    __shared__ __align__(16) unsigned short colsLds[16][CAPT];
    int wave = threadIdx.x >> 6;
    int node = blockIdx.x * 16 + wave;        // NN = 625*16 exactly
    gather_mean(h0, cnt8, node, colb + (size_t)node * CAPT,
                &colsLds[wave][0], &ms[wave][0]);

    f32x4 acc[1] = {};
    if (wave < 8)
        mfma_cols<HF, 1>(blockIdx.x, wave * 16, h0, HF, Wr, acc);  // h0 @ Wr1
    __syncthreads();
    if (wave < 8) {
        mfma_cols<HF, 1>(0, wave * 16, &ms[0][0], LDP, Wl, acc);   // + means @ Wl1
        epilogue_n<1, true, false, true>(blockIdx.x, wave * 16, HF, bias, acc, h1);
    }
}

// ---------------- aggfin2cls: agg + sage2 GEMM + relu + classifier ----------------
// Same structure; h2 row-tile lives only in LDS (padded), classifier runs from it.
__global__ __launch_bounds__(1024)
void aggfin2cls_k(const unsigned short* __restrict__ h1, const int* __restrict__ cnt8,
                  const unsigned short* __restrict__ colb,
                  const unsigned short* __restrict__ Wr, const unsigned short* __restrict__ Wl,
                  const float* __restrict__ bias, const unsigned short* __restrict__ Wc,
                  float* __restrict__ out) {
    __shared__ __align__(16) unsigned short ms[16][LDP];
    __shared__ __align__(16) unsigned short h2s[16][LDP];
    __shared__ __align__(16) unsigned short colsLds[16][CAPT];
    int wave = threadIdx.x >> 6;
    int lane = threadIdx.x & 63;
    int m = lane & 15, quad = lane >> 4;
    int node = blockIdx.x * 16 + wave;
    gather_mean(h1, cnt8, node, colb + (size_t)node * CAPT,
                &colsLds[wave][0], &ms[wave][0]);

    f32x4 acc[1] = {};
    if (wave < 8)
        mfma_cols<HF, 1>(blockIdx.x, wave * 16, h1, HF, Wr, acc);  // h1 @ Wr2
    __syncthreads();
    if (wave < 8) {
        mfma_cols<HF, 1>(0, wave * 16, &ms[0][0], LDP, Wl, acc);   // + means @ Wl2
        int colg = wave * 16 + m;
        float bv = bias[colg];
#pragma unroll
        for (int r = 0; r < 4; ++r) {
            float v = acc[0][r] + bv;
            h2s[quad * 4 + r][colg] = f2bf(fmaxf(v, 0.f));         // relu -> LDS
        }
    }
    __syncthreads();
    if (wave < 4) {
        f32x4 cacc[1] = {};
        mfma_cols<HF, 1>(0, wave * 16, &h2s[0][0], LDP, Wc, cacc); // h2 @ W_cls
        epilogue_n<1, false, false, false>(blockIdx.x, wave * 16, CLS,
                                           nullptr, cacc, out);
    }
}

// ---------------- launch ----------------

extern "C" void kernel_launch(void* const* d_in, const int* in_sizes, int n_in,
                              void* d_out, int out_size, void* d_ws, size_t ws_size,
                              hipStream_t stream) {
    const float* x      = (const float*)d_in[0];
    const int*   ei     = (const int*)d_in[1];
    const float* W_lin  = (const float*)d_in[2];
    const float* b_lin  = (const float*)d_in[3];
    const float* Wl1    = (const float*)d_in[4];
    const float* bl1    = (const float*)d_in[5];
    const float* Wr1    = (const float*)d_in[6];
    const float* Wl2    = (const float*)d_in[7];
    const float* bl2    = (const float*)d_in[8];
    const float* Wr2    = (const float*)d_in[9];
    const float* W_cls  = (const float*)d_in[10];
    float* out = (float*)d_out;

    const int E = in_sizes[1] / 2;
    const int* src = ei;
    const int* dst = ei + E;

    // workspace layout (bf16 stored as ushort)
    unsigned short* wb  = (unsigned short*)d_ws;          // 73728 weights bf16
    unsigned short* wbl1 = wb;
    unsigned short* wbr1 = wb + 16384;
    unsigned short* wbl2 = wb + 32768;
    unsigned short* wbr2 = wb + 49152;
    unsigned short* wbc  = wb + 65536;
    unsigned short* h0  = wb + 73728;                     // NN*HF
    unsigned short* h1  = h0 + (size_t)NN * HF;           // NN*HF
    int* cnt8 = (int*)(h1 + (size_t)NN * HF);             // NR*NP
    unsigned short* colb = (unsigned short*)(cnt8 + NR * NP);  // NN*CAPT

    hipMemsetAsync(cnt8, 0, NR * NP * sizeof(int), stream);

    // ---- fused: input projection + relu || segmented fill || weight cvt ----
    fused_k<<<GB + FB + CB, 256, 0, stream>>>(
        x, W_lin, b_lin, h0, src, dst, cnt8, colb, E,
        Wl1, Wr1, Wl2, Wr2, W_cls, wb);

    // ---- sage1 (agg + GEMM fused) ----
    aggfin1_k<<<RT, 1024, 0, stream>>>(h0, cnt8, colb, wbr1, wbl1, bl1, h1);

    // ---- sage2 + relu + classifier (agg + GEMMs fused) ----
    aggfin2cls_k<<<RT, 1024, 0, stream>>>(h1, cnt8, colb, wbr2, wbl2, bl2, wbc, out);
}